// Round 1
// baseline (761.639 us; speedup 1.0000x reference)
//
#include <hip/hip_runtime.h>
#include <cstdint>

// FLossNoSoftMax: result = -sum_rows( mean_v( (1-top5mask)*log(1-x) ) )
// = -sum_rows( (sum_all log(1-x) - sum_top5 log(1-x)) / V )

#define MAXK 8
constexpr int NT = 256;
constexpr int V_DIM = 50257;

__global__ __launch_bounds__(NT) void floss_row_kernel(
    const int* __restrict__ top_c_p,
    const float* __restrict__ out,
    float* __restrict__ row_loss,
    int B, int V)
{
    const int row = blockIdx.x;
    if (row >= B) return;
    int k = *top_c_p;
    k = k < 0 ? 0 : (k > MAXK ? MAXK : k);

    const float* rowp = out + (size_t)row * (size_t)V;
    const int tid = threadIdx.x;

    float sum = 0.0f;
    float t[MAXK];               // sorted ascending; t[0] = current k-th largest
    #pragma unroll
    for (int i = 0; i < MAXK; ++i) t[i] = -INFINITY;

    auto proc = [&](float x) {
        sum += __logf(1.0f - x);
        if (x > t[0]) {          // rare (E[inserts] ~ 18 per thread)
            int i = 1;
            for (; i < k && x > t[i]; ++i) t[i - 1] = t[i];
            t[i - 1] = x;
        }
    };

    // Row base is only 4B-aligned in general (V % 4 == 1): scalar prologue to
    // 16B alignment, float4 body, scalar tail.
    uintptr_t addr = (uintptr_t)rowp;
    int pre = (int)(((16u - (unsigned)(addr & 15u)) & 15u) >> 2);
    if (pre > V) pre = V;
    int nvec = (V - pre) >> 2;
    int post = V - pre - (nvec << 2);

    for (int i = tid; i < pre; i += NT) proc(rowp[i]);
    const float4* vp = (const float4*)(rowp + pre);
    for (int i = tid; i < nvec; i += NT) {
        float4 v = vp[i];
        proc(v.x); proc(v.y); proc(v.z); proc(v.w);
    }
    const float* tailp = rowp + pre + (nvec << 2);
    for (int i = tid; i < post; i += NT) proc(tailp[i]);

    // Block reduction: sum + merge of per-thread top-k lists (descending).
    __shared__ float s_sum[NT];
    __shared__ float s_top[NT][MAXK];
    s_sum[tid] = sum;
    #pragma unroll
    for (int j = 0; j < MAXK; ++j)
        s_top[tid][j] = (j < k) ? t[k - 1 - j] : -INFINITY;

    for (int s = NT / 2; s > 0; s >>= 1) {
        __syncthreads();
        if (tid < s) {
            s_sum[tid] += s_sum[tid + s];
            float a[MAXK], b[MAXK], c[MAXK];
            for (int j = 0; j < k; ++j) { a[j] = s_top[tid][j]; b[j] = s_top[tid + s][j]; }
            int ia = 0, ib = 0;
            for (int j = 0; j < k; ++j) c[j] = (a[ia] >= b[ib]) ? a[ia++] : b[ib++];
            for (int j = 0; j < k; ++j) s_top[tid][j] = c[j];
        }
    }
    __syncthreads();
    if (tid == 0) {
        float tops = 0.0f;
        for (int j = 0; j < k; ++j) tops += __logf(1.0f - s_top[0][j]);
        row_loss[row] = (s_sum[0] - tops) / (float)V;
    }
}

// Deterministic final reduce (no float atomics -> bit-stable across replays).
__global__ __launch_bounds__(NT) void floss_final_kernel(
    const float* __restrict__ row_loss, float* __restrict__ res, int B)
{
    __shared__ float s[NT];
    float acc = 0.0f;
    for (int i = threadIdx.x; i < B; i += NT) acc += row_loss[i];
    s[threadIdx.x] = acc;
    for (int st = NT / 2; st > 0; st >>= 1) {
        __syncthreads();
        if (threadIdx.x < st) s[threadIdx.x] += s[threadIdx.x + st];
    }
    __syncthreads();
    if (threadIdx.x == 0) *res = -s[0];
}

extern "C" void kernel_launch(void* const* d_in, const int* in_sizes, int n_in,
                              void* d_out, int out_size, void* d_ws, size_t ws_size,
                              hipStream_t stream) {
    const int*   top_c  = (const int*)d_in[0];
    const float* output = (const float*)d_in[1];
    const int V = V_DIM;
    const int B = in_sizes[1] / V;

    float* row_loss = (float*)d_ws;  // B floats of scratch

    floss_row_kernel<<<B, NT, 0, stream>>>(top_c, output, row_loss, B, V);
    floss_final_kernel<<<1, NT, 0, stream>>>(row_loss, (float*)d_out, B);
}

// Round 2
// 138.343 us; speedup vs baseline: 5.5055x; 5.5055x over previous
//
#include <hip/hip_runtime.h>
#include <cstdint>

// FLossNoSoftMax: result = -sum_rows( (sum_all log(1-x) - sum_topk log(1-x)) / V )
// All top-k state kept in registers via static indexing (no scratch).

#define MAXK 8
constexpr int NT = 256;
constexpr int V_DIM = 50257;

__global__ __launch_bounds__(NT) void floss_row_kernel(
    const int* __restrict__ top_c_p,
    const float* __restrict__ out,
    float* __restrict__ row_loss,
    int B, int V)
{
    const int row = blockIdx.x;
    if (row >= B) return;
    int k = *top_c_p;
    k = k < 0 ? 0 : (k > MAXK ? MAXK : k);

    const float* rowp = out + (size_t)row * (size_t)V;
    const int tid = threadIdx.x;

    float sum0 = 0.0f, sum1 = 0.0f;
    float d[MAXK];               // sorted DESCENDING top-8, all static-indexed
    #pragma unroll
    for (int i = 0; i < MAXK; ++i) d[i] = -INFINITY;

    // Branchless sorted-descending insert (drops d[7]); no-op if x <= d[7].
    auto insert = [&](float x) {
        float nd[MAXK];
        nd[0] = fmaxf(d[0], x);
        #pragma unroll
        for (int i = 1; i < MAXK; ++i)
            nd[i] = (x > d[i - 1]) ? d[i - 1] : fmaxf(d[i], x);
        #pragma unroll
        for (int i = 0; i < MAXK; ++i) d[i] = nd[i];
    };

    auto proc1 = [&](float x) {
        sum0 += __logf(1.0f - x);
        insert(x);
    };
    auto proc4 = [&](float4 v) {
        sum0 += __logf(1.0f - v.x) + __logf(1.0f - v.y);
        sum1 += __logf(1.0f - v.z) + __logf(1.0f - v.w);
        float mx = fmaxf(fmaxf(v.x, v.y), fmaxf(v.z, v.w));
        if (mx > d[MAXK - 1]) {          // register compare; wave skips when no lane inserts
            insert(v.x); insert(v.y); insert(v.z); insert(v.w);
        }
    };

    // Row base is only 4B-aligned (V % 4 == 1): scalar prologue to 16B, float4 body, tail.
    uintptr_t addr = (uintptr_t)rowp;
    int pre = (int)(((16u - (unsigned)(addr & 15u)) & 15u) >> 2);
    if (pre > V) pre = V;
    int nvec = (V - pre) >> 2;
    int post = V - pre - (nvec << 2);

    for (int i = tid; i < pre; i += NT) proc1(rowp[i]);
    const float4* vp = (const float4*)(rowp + pre);
    for (int i = tid; i < nvec; i += NT) proc4(vp[i]);
    const float* tailp = rowp + pre + (nvec << 2);
    for (int i = tid; i < post; i += NT) proc1(tailp[i]);

    float sum = sum0 + sum1;

    // Block reduction: sum + static merge-network of sorted top-8 lists.
    __shared__ float s_sum[NT];
    __shared__ float s_top[NT][MAXK + 1];   // +1 pad: stride 9 vs 32 banks -> conflict-free
    s_sum[tid] = sum;
    #pragma unroll
    for (int j = 0; j < MAXK; ++j) s_top[tid][j] = d[j];

    for (int s = NT / 2; s > 0; s >>= 1) {
        __syncthreads();
        if (tid < s) {
            s_sum[tid] += s_sum[tid + s];
            float a[MAXK], b[MAXK], c[MAXK];
            #pragma unroll
            for (int j = 0; j < MAXK; ++j) { a[j] = s_top[tid][j]; b[j] = s_top[tid + s][j]; }
            // r-th largest of union = max_{i=0..r} min(A_i, B_{r-i}), A_0=B_0=+inf
            #pragma unroll
            for (int r = 1; r <= MAXK; ++r) {
                float best = fmaxf(b[r - 1], a[r - 1]);   // i=0 and i=r terms
                #pragma unroll
                for (int i = 1; i < r; ++i)
                    best = fmaxf(best, fminf(a[i - 1], b[r - i - 1]));
                c[r - 1] = best;
            }
            #pragma unroll
            for (int j = 0; j < MAXK; ++j) s_top[tid][j] = c[j];
        }
    }
    __syncthreads();
    if (tid == 0) {
        float tops = 0.0f;
        for (int j = 0; j < k; ++j) tops += __logf(1.0f - s_top[0][j]);
        row_loss[row] = (s_sum[0] - tops) / (float)V;
    }
}

// Deterministic final reduce (no float atomics -> bit-stable across replays).
__global__ __launch_bounds__(NT) void floss_final_kernel(
    const float* __restrict__ row_loss, float* __restrict__ res, int B)
{
    __shared__ float s[NT];
    float acc = 0.0f;
    for (int i = threadIdx.x; i < B; i += NT) acc += row_loss[i];
    s[threadIdx.x] = acc;
    for (int st = NT / 2; st > 0; st >>= 1) {
        __syncthreads();
        if (threadIdx.x < st) s[threadIdx.x] += s[threadIdx.x + st];
    }
    __syncthreads();
    if (threadIdx.x == 0) *res = -s[0];
}

extern "C" void kernel_launch(void* const* d_in, const int* in_sizes, int n_in,
                              void* d_out, int out_size, void* d_ws, size_t ws_size,
                              hipStream_t stream) {
    const int*   top_c  = (const int*)d_in[0];
    const float* output = (const float*)d_in[1];
    const int V = V_DIM;
    const int B = in_sizes[1] / V;

    float* row_loss = (float*)d_ws;  // B floats of scratch

    floss_row_kernel<<<B, NT, 0, stream>>>(top_c, output, row_loss, B, V);
    floss_final_kernel<<<1, NT, 0, stream>>>(row_loss, (float*)d_out, B);
}

// Round 3
// 88.928 us; speedup vs baseline: 8.5647x; 1.5557x over previous
//
#include <hip/hip_runtime.h>
#include <cstdint>

// FLossNoSoftMax: result = -sum_rows( (sum_all log(1-x) - sum_topk log(1-x)) / V )
// Hot loop: top-8 via med3 chain (8 VALU/elem), sum-of-logs via log-of-product
// with bit-op renormalization (no per-element transcendental).

#define MAXK 8
constexpr int NT = 256;
constexpr int NW = NT / 64;
constexpr int V_DIM = 50257;
constexpr float LN2F = 0.69314718055994530942f;

__device__ __forceinline__ float med3f(float a, float b, float c) {
    return __builtin_amdgcn_fmed3f(a, b, c);
}

// d (sorted desc) <- top-8 of d ∪ {x}; in-place, all static indices.
__device__ __forceinline__ void insert8(float (&d)[MAXK], float x) {
    #pragma unroll
    for (int i = MAXK - 1; i >= 1; --i)
        d[i] = med3f(x, d[i - 1], d[i]);   // reads old d[i-1], d[i]
    d[0] = fmaxf(d[0], x);
}

// a <- top-8 (sorted desc) of a ∪ b, both sorted desc.
// maxpair gives a bitonic sequence containing the top-8; bitonic-merge sorts it.
__device__ __forceinline__ void merge8(float (&a)[MAXK], const float (&b)[MAXK]) {
    float m[MAXK];
    #pragma unroll
    for (int i = 0; i < MAXK; ++i) m[i] = fmaxf(a[i], b[MAXK - 1 - i]);
    #pragma unroll
    for (int off = MAXK / 2; off >= 1; off >>= 1) {
        #pragma unroll
        for (int i = 0; i < MAXK; ++i) {
            if ((i & off) == 0) {
                float hi = fmaxf(m[i], m[i + off]);
                float lo = fminf(m[i], m[i + off]);
                m[i] = hi; m[i + off] = lo;
            }
        }
    }
    #pragma unroll
    for (int i = 0; i < MAXK; ++i) a[i] = m[i];
}

__global__ __launch_bounds__(NT) void floss_row_kernel(
    const int* __restrict__ top_c_p,
    const float* __restrict__ out,
    float* __restrict__ row_loss,
    int B, int V)
{
    const int row = blockIdx.x;
    if (row >= B) return;
    int k = *top_c_p;
    k = k < 0 ? 0 : (k > MAXK ? MAXK : k);

    const float* rowp = out + (size_t)row * (size_t)V;
    const int tid = threadIdx.x;

    float d[MAXK];
    #pragma unroll
    for (int i = 0; i < MAXK; ++i) d[i] = -INFINITY;

    float lnsum = 0.0f;                  // scalar-path partial (pre/tail elems)
    float mant0 = 1.0f, mant1 = 1.0f;    // running product mantissas in [0.5,1)
    int   e0 = 0, e1 = 0;                // accumulated base-2 exponents

    auto proc4 = [&](float4 v, float& mant, int& esum) {
        insert8(d, v.x); insert8(d, v.y); insert8(d, v.z); insert8(d, v.w);
        float p = ((1.0f - v.x) * (1.0f - v.y)) * ((1.0f - v.z) * (1.0f - v.w));
        mant *= p;   // >= 0.5 * 2^-96 -> always normal
        int bits = __float_as_int(mant);
        esum += ((bits >> 23) & 0xff) - 126;
        mant = __int_as_float((bits & 0x807fffff) | 0x3f000000);  // back to [0.5,1)
    };
    auto proc1 = [&](float x) {
        insert8(d, x);
        lnsum += __logf(1.0f - x);
    };

    // Row base only 4B-aligned (V%4==1): scalar prologue to 16B, float4 body, tail.
    uintptr_t addr = (uintptr_t)rowp;
    int pre = (int)(((16u - (unsigned)(addr & 15u)) & 15u) >> 2);
    if (pre > V) pre = V;
    int nvec = (V - pre) >> 2;
    int post = V - pre - (nvec << 2);

    for (int i = tid; i < pre; i += NT) proc1(rowp[i]);
    const float4* vp = (const float4*)(rowp + pre);
    int i = tid;
    for (; i + NT < nvec; i += 2 * NT) {
        float4 va = vp[i];
        float4 vb = vp[i + NT];
        proc4(va, mant0, e0);
        proc4(vb, mant1, e1);
    }
    for (; i < nvec; i += NT) proc4(vp[i], mant0, e0);
    const float* tailp = rowp + pre + (nvec << 2);
    for (int ii = tid; ii < post; ii += NT) proc1(tailp[ii]);

    float lane_ln = lnsum + (float)(e0 + e1) * LN2F + __logf(mant0) + __logf(mant1);

    // Intra-wave butterfly: sum + top-8 merge.
    #pragma unroll
    for (int off = 1; off < 64; off <<= 1) {
        lane_ln += __shfl_xor(lane_ln, off);
        float b[MAXK];
        #pragma unroll
        for (int j = 0; j < MAXK; ++j) b[j] = __shfl_xor(d[j], off);
        merge8(d, b);
    }

    // Inter-wave via LDS (4 waves).
    __shared__ float s_sum[NW];
    __shared__ float s_top[NW][MAXK];
    const int wid = tid >> 6, lane = tid & 63;
    if (lane == 0) {
        s_sum[wid] = lane_ln;
        #pragma unroll
        for (int j = 0; j < MAXK; ++j) s_top[wid][j] = d[j];
    }
    __syncthreads();
    if (tid == 0) {
        float tot = s_sum[0] + s_sum[1] + s_sum[2] + s_sum[3];
        float a[MAXK], b[MAXK];
        #pragma unroll
        for (int j = 0; j < MAXK; ++j) a[j] = s_top[0][j];
        #pragma unroll
        for (int w = 1; w < NW; ++w) {
            #pragma unroll
            for (int j = 0; j < MAXK; ++j) b[j] = s_top[w][j];
            merge8(a, b);
        }
        float tops = 0.0f;
        #pragma unroll
        for (int j = 0; j < MAXK; ++j)
            tops += (j < k) ? __logf(1.0f - a[j]) : 0.0f;
        row_loss[row] = (tot - tops) / (float)V;
    }
}

// Deterministic final reduce (no float atomics -> bit-stable across replays).
__global__ __launch_bounds__(NT) void floss_final_kernel(
    const float* __restrict__ row_loss, float* __restrict__ res, int B)
{
    __shared__ float s[NT];
    float acc = 0.0f;
    for (int i = threadIdx.x; i < B; i += NT) acc += row_loss[i];
    s[threadIdx.x] = acc;
    for (int st = NT / 2; st > 0; st >>= 1) {
        __syncthreads();
        if (threadIdx.x < st) s[threadIdx.x] += s[threadIdx.x + st];
    }
    __syncthreads();
    if (threadIdx.x == 0) *res = -s[0];
}

extern "C" void kernel_launch(void* const* d_in, const int* in_sizes, int n_in,
                              void* d_out, int out_size, void* d_ws, size_t ws_size,
                              hipStream_t stream) {
    const int*   top_c  = (const int*)d_in[0];
    const float* output = (const float*)d_in[1];
    const int V = V_DIM;
    const int B = in_sizes[1] / V;

    float* row_loss = (float*)d_ws;  // B floats of scratch

    floss_row_kernel<<<B, NT, 0, stream>>>(top_c, output, row_loss, B, V);
    floss_final_kernel<<<1, NT, 0, stream>>>(row_loss, (float*)d_out, B);
}